// Round 1
// baseline (2477.795 us; speedup 1.0000x reference)
//
#include <hip/hip_runtime.h>
#include <math.h>

// Problem constants
#define V_  8185
#define E_  353
#define H_  191
#define FH_ 764
#define Z_  13
#define T_  25
#define START_ 19
#define VP_ 8192
#define NT_ 64   // logits col-tiles (128 cols each)

__device__ __forceinline__ float sigf(float x) { return 1.0f / (1.0f + expf(-x)); }

// ---------------------------------------------------------------------------
// Pad out_w (191 x 8185) -> WP (191 x 8192), zero tail, for aligned loads.
// ---------------------------------------------------------------------------
__global__ __launch_bounds__(256) void pad_w_kernel(const float* __restrict__ src,
                                                    float* __restrict__ dst) {
  int i = blockIdx.x * 256 + threadIdx.x;
  if (i >= H_ * VP_) return;
  int k = i >> 13;            // row (VP_=8192=2^13)
  int j = i & (VP_ - 1);      // col
  dst[i] = (j < V_) ? src[(size_t)k * V_ + j] : 0.0f;
}

// ---------------------------------------------------------------------------
// Combined EK/XK precompute:  C[M][764] = A_rows[M][353] @ W[353][764]
//   blockIdx.y <  yA : A row m = emb[m]                       (EK, M=V)
//   blockIdx.y >= yA : A row m=(t*B+b) -> emb[inputs[b*T+t]]  (XK, M=T*B)
// Tile: 32 rows x 256 cols, 256 threads, 8 rows x 4 cols per thread.
// AT layout [k][32] (transposed); in-loop reads are wave-broadcast.
// ---------------------------------------------------------------------------
#define FMA4(A, S) \
  A.x = fmaf(S, wv.x, A.x); A.y = fmaf(S, wv.y, A.y); \
  A.z = fmaf(S, wv.z, A.z); A.w = fmaf(S, wv.w, A.w);

__global__ __launch_bounds__(256) void gemm_ew(const float* __restrict__ emb,
                                               const float* __restrict__ Wa,
                                               float* __restrict__ Ca, int Ma,
                                               const float* __restrict__ Wb,
                                               float* __restrict__ Cb, int Mb,
                                               const int* __restrict__ inputs,
                                               int B, int yA) {
  __shared__ __align__(16) float AT[32 * E_];   // [k][32]
  const int tid = threadIdx.x;
  const int n0 = blockIdx.x * 256;
  int yb = blockIdx.y;
  const float* W; float* C; int M; int gatherB;
  if (yb < yA) { W = Wa; C = Ca; M = Ma; gatherB = 0; }
  else { yb -= yA; W = Wb; C = Cb; M = Mb; gatherB = 1; }
  const int m0 = yb * 32;

  for (int i = tid; i < 32 * E_; i += 256) {
    int r = i & 31, k = i >> 5;
    int m = m0 + r;
    float v = 0.0f;
    if (m < M) {
      int row;
      if (gatherB == 0) row = m;
      else { int tt = m / B, b = m - tt * B; row = inputs[b * T_ + tt]; }
      v = emb[(size_t)row * E_ + k];
    }
    AT[i] = v;
  }
  __syncthreads();

  const int lane = tid & 63;
  const int w8 = (tid >> 6) * 8;
  const int j = n0 + lane * 4;
  if (j >= FH_) return;  // 764 % 4 == 0: lanes fully valid or fully out
  float4 a0 = {0,0,0,0}, a1 = {0,0,0,0}, a2 = {0,0,0,0}, a3 = {0,0,0,0};
  float4 a4 = {0,0,0,0}, a5 = {0,0,0,0}, a6 = {0,0,0,0}, a7 = {0,0,0,0};
  const float* wc = W + j;
  const float* at = AT + w8;
#pragma unroll 2
  for (int k = 0; k < E_; ++k) {
    float4 wv = *(const float4*)(wc + (size_t)k * FH_);
    float4 r03 = *(const float4*)(at + k * 32);
    float4 r47 = *(const float4*)(at + k * 32 + 4);
    FMA4(a0, r03.x) FMA4(a1, r03.y) FMA4(a2, r03.z) FMA4(a3, r03.w)
    FMA4(a4, r47.x) FMA4(a5, r47.y) FMA4(a6, r47.z) FMA4(a7, r47.w)
  }
  const int mb = m0 + w8;
  float4 accs[8] = {a0, a1, a2, a3, a4, a5, a6, a7};
#pragma unroll
  for (int r = 0; r < 8; ++r)
    if (mb + r < M) *(float4*)(C + (size_t)(mb + r) * FH_ + j) = accs[r];
}

// ---------------------------------------------------------------------------
// Whole encoder + latent + decoder init in ONE kernel.
// Batch rows are independent across the recurrence, so each block owns 2 rows
// and runs all 25 steps with h/c/gates in LDS — no syncs, no launches.
// 192 threads = 191 active col-quads of the 764 gate columns.
// inf_rk (583 KB) is read per step from (XCD-local) L2.
// ---------------------------------------------------------------------------
__global__ __launch_bounds__(192) void encoder_all(
    const float* __restrict__ xk,    // XK: (T*B, 764), row (t*B + b)
    const float* __restrict__ rk,    // inf_rk (191, 764)
    const float* __restrict__ bias,  // inf_b (764)
    const float* __restrict__ eps,
    const float* __restrict__ mu_w, const float* __restrict__ mu_b,
    const float* __restrict__ sig_w, const float* __restrict__ sig_b,
    const float* __restrict__ iw, const float* __restrict__ ib,
    float* __restrict__ h0o, float* __restrict__ c0o, int B) {
  __shared__ float h[2][H_], c[2][H_];
  __shared__ __align__(16) float g[2][FH_];
  __shared__ float zs[2][Z_];
  const int tid = threadIdx.x;
  const int b0 = blockIdx.x * 2;

  if (tid < H_) {
    h[0][tid] = 0.0f; h[1][tid] = 0.0f;
    c[0][tid] = 0.0f; c[1][tid] = 0.0f;
  }
  const bool act = tid < (FH_ / 4);       // 191 quads cover 764 cols
  const int q4 = tid * 4;
  float4 b4 = act ? *(const float4*)(bias + q4) : make_float4(0, 0, 0, 0);
  const float* rkq = rk + q4;
  __syncthreads();

  for (int t = 0; t < T_; ++t) {
    if (act) {
      const float* xr = xk + ((size_t)t * B + b0) * FH_ + q4;
      float4 x0 = *(const float4*)(xr);
      float4 x1 = *(const float4*)(xr + FH_);
      float4 a0 = {0,0,0,0}, a1 = {0,0,0,0};
#pragma unroll 4
      for (int k = 0; k < H_; ++k) {
        float4 wv = *(const float4*)(rkq + (size_t)k * FH_);
        float h0v = h[0][k], h1v = h[1][k];
        a0.x = fmaf(h0v, wv.x, a0.x); a0.y = fmaf(h0v, wv.y, a0.y);
        a0.z = fmaf(h0v, wv.z, a0.z); a0.w = fmaf(h0v, wv.w, a0.w);
        a1.x = fmaf(h1v, wv.x, a1.x); a1.y = fmaf(h1v, wv.y, a1.y);
        a1.z = fmaf(h1v, wv.z, a1.z); a1.w = fmaf(h1v, wv.w, a1.w);
      }
      float4 g0 = make_float4(a0.x + x0.x + b4.x, a0.y + x0.y + b4.y,
                              a0.z + x0.z + b4.z, a0.w + x0.w + b4.w);
      float4 g1 = make_float4(a1.x + x1.x + b4.x, a1.y + x1.y + b4.y,
                              a1.z + x1.z + b4.z, a1.w + x1.w + b4.w);
      *(float4*)(&g[0][q4]) = g0;
      *(float4*)(&g[1][q4]) = g1;
    }
    __syncthreads();
    if (tid < H_) {
#pragma unroll
      for (int r = 0; r < 2; ++r) {
        float gi = g[r][tid], gf = g[r][H_ + tid];
        float gg = g[r][2 * H_ + tid], go = g[r][3 * H_ + tid];
        float cn = sigf(gf) * c[r][tid] + sigf(gi) * tanhf(gg);
        c[r][tid] = cn;
        h[r][tid] = sigf(go) * tanhf(cn);
      }
    }
    __syncthreads();
  }

  // latent: mu/sigma/z, then decoder init state h0 = c0 = z @ init_w + init_b
  if (tid < 2 * Z_) {
    int r = tid / Z_, zq = tid - r * Z_;
    float mu = mu_b[zq], sg = sig_b[zq];
    for (int k = 0; k < H_; ++k) {
      float hv = h[r][k];
      mu = fmaf(hv, mu_w[k * Z_ + zq], mu);
      sg = fmaf(hv, sig_w[k * Z_ + zq], sg);
    }
    zs[r][zq] = mu + eps[zq] * sg;
  }
  __syncthreads();
  if (tid < H_) {
#pragma unroll
    for (int r = 0; r < 2; ++r) {
      float acc = ib[tid];
#pragma unroll
      for (int z = 0; z < Z_; ++z) acc = fmaf(zs[r][z], iw[z * H_ + tid], acc);
      h0o[(size_t)(b0 + r) * H_ + tid] = acc;
      c0o[(size_t)(b0 + r) * H_ + tid] = acc;
    }
  }
}

// ---------------------------------------------------------------------------
// Decoder LSTM step: argmax-reduce of previous logits partials -> token ->
// gates = EK[token] + h@rk + b -> h/c update.
// Block owns h-cols [c0,c0+8) x 16 batch rows. Grid (24, B/16).
// ---------------------------------------------------------------------------
__global__ __launch_bounds__(256) void lstm_step(const float* __restrict__ ek,
                                                 const float* __restrict__ rk,
                                                 const float* __restrict__ bias,
                                                 const float* __restrict__ h_in,
                                                 const float* __restrict__ c_in,
                                                 float* __restrict__ h_out,
                                                 float* __restrict__ c_out,
                                                 const float* __restrict__ pmax,
                                                 const int* __restrict__ pidx,
                                                 int first) {
  __shared__ float hs[16 * H_];
  __shared__ float xs[16 * 32];
  __shared__ float bs[32];
  __shared__ int   tk[16];
  __shared__ float pv[16 * NT_];
  __shared__ int   pi[16 * NT_];
  __shared__ float gb[32 * 16];

  const int tid = threadIdx.x;
  const int c0 = blockIdx.x * 8;
  const int m0 = blockIdx.y * 16;

  if (first) {
    if (tid < 16) tk[tid] = START_;
  } else {
    for (int i = tid; i < 16 * NT_; i += 256) {
      int row = i / NT_, s = i - row * NT_;
      pv[i] = pmax[(size_t)(m0 + row) * NT_ + s];
      pi[i] = pidx[(size_t)(m0 + row) * NT_ + s];
    }
    __syncthreads();
    if (tid < 16) {
      float bv = pv[tid * NT_]; int bi = pi[tid * NT_];
      for (int s = 1; s < NT_; ++s) {
        float v = pv[tid * NT_ + s]; int ii = pi[tid * NT_ + s];
        if (v > bv || (v == bv && ii < bi)) { bv = v; bi = ii; }
      }
      tk[tid] = bi;
    }
  }
  __syncthreads();

  // stage h rows (contiguous copy)
  for (int i = tid; i < 16 * H_; i += 256) hs[i] = h_in[(size_t)m0 * H_ + i];
  // stage x gate values and bias for this block's 32 gate columns
  for (int i = tid; i < 16 * 32; i += 256) {
    int row = i >> 5, q = i & 31;
    int jj = c0 + (q & 7);
    int jg = jj + H_ * (q >> 3);
    float xv = 0.0f;
    if (jj < H_) xv = ek[(size_t)tk[row] * FH_ + jg];
    xs[i] = xv;
  }
  if (tid < 32) {
    int jj = c0 + (tid & 7);
    bs[tid] = (jj < H_) ? bias[jj + H_ * (tid >> 3)] : 0.0f;
  }
  __syncthreads();

  // recurrent dot: thread = (gate-col slot q, row-group rg); 2 rows each
  const int q = tid & 31, rg = tid >> 5;
  const int jj = c0 + (q & 7);
  const int jg = jj + H_ * (q >> 3);
  float a0 = 0.0f, a1 = 0.0f;
  if (jj < H_) {
    const float* rkp = rk + jg;
    const float* h0p = hs + rg * H_;
    const float* h1p = hs + (rg + 8) * H_;
    for (int k = 0; k < H_; ++k) {
      float wv = rkp[(size_t)k * FH_];
      a0 = fmaf(h0p[k], wv, a0);
      a1 = fmaf(h1p[k], wv, a1);
    }
  }
  gb[q * 16 + rg] = a0;
  gb[q * 16 + rg + 8] = a1;
  __syncthreads();

  // pointwise LSTM update for (8 cols x 16 rows)
  if (tid < 128) {
    int cc = tid & 7, row = tid >> 3;
    int jc = c0 + cc;
    if (jc < H_) {
      float gi = gb[(cc      ) * 16 + row] + xs[row * 32 + cc      ] + bs[cc];
      float gf = gb[( 8 + cc ) * 16 + row] + xs[row * 32 +  8 + cc ] + bs[ 8 + cc];
      float gg = gb[(16 + cc ) * 16 + row] + xs[row * 32 + 16 + cc ] + bs[16 + cc];
      float go = gb[(24 + cc ) * 16 + row] + xs[row * 32 + 24 + cc ] + bs[24 + cc];
      float co = c_in[(size_t)(m0 + row) * H_ + jc];
      float cn = sigf(gf) * co + sigf(gi) * tanhf(gg);
      float hn = sigf(go) * tanhf(cn);
      c_out[(size_t)(m0 + row) * H_ + jc] = cn;
      h_out[(size_t)(m0 + row) * H_ + jc] = hn;
    }
  }
}

// ---------------------------------------------------------------------------
// logits = h @ WP + out_b ; write out[:, t, :]; per-(row, col-tile) argmax
// partials. Tile 32 rows x 128 cols, 256 threads (8 rows x 2 cols/thread).
// Grid (NT_=64, B/32). WP re-read 8x/step (was 16x).
// ---------------------------------------------------------------------------
__global__ __launch_bounds__(256) void logits_argmax(const float* __restrict__ h,
                                                     const float* __restrict__ wp,
                                                     const float* __restrict__ ob,
                                                     float* __restrict__ out, int t,
                                                     float* __restrict__ pmax,
                                                     int* __restrict__ pidx) {
  __shared__ __align__(16) float AT[32 * H_];   // [k][32]
  const int tid = threadIdx.x;
  const int n0 = blockIdx.x * 128;
  const int m0 = blockIdx.y * 32;
  for (int i = tid; i < 32 * H_; i += 256) {
    int r = i & 31, k = i >> 5;
    AT[i] = h[(size_t)(m0 + r) * H_ + k];   // h tile (24.4 KB) is L1/L2-hot
  }
  __syncthreads();

  const int lane = tid & 63;
  const int w8 = (tid >> 6) * 8;
  const int j = n0 + lane * 2;
  float2 acc[8];
#pragma unroll
  for (int r = 0; r < 8; ++r) acc[r] = make_float2(0.0f, 0.0f);
  const float* wc = wp + j;
  const float* at = AT + w8;
#pragma unroll 2
  for (int k = 0; k < H_; ++k) {
    float2 wv = *(const float2*)(wc + (size_t)k * VP_);
    float4 r03 = *(const float4*)(at + k * 32);       // wave-broadcast reads
    float4 r47 = *(const float4*)(at + k * 32 + 4);
    acc[0].x = fmaf(r03.x, wv.x, acc[0].x); acc[0].y = fmaf(r03.x, wv.y, acc[0].y);
    acc[1].x = fmaf(r03.y, wv.x, acc[1].x); acc[1].y = fmaf(r03.y, wv.y, acc[1].y);
    acc[2].x = fmaf(r03.z, wv.x, acc[2].x); acc[2].y = fmaf(r03.z, wv.y, acc[2].y);
    acc[3].x = fmaf(r03.w, wv.x, acc[3].x); acc[3].y = fmaf(r03.w, wv.y, acc[3].y);
    acc[4].x = fmaf(r47.x, wv.x, acc[4].x); acc[4].y = fmaf(r47.x, wv.y, acc[4].y);
    acc[5].x = fmaf(r47.y, wv.x, acc[5].x); acc[5].y = fmaf(r47.y, wv.y, acc[5].y);
    acc[6].x = fmaf(r47.z, wv.x, acc[6].x); acc[6].y = fmaf(r47.z, wv.y, acc[6].y);
    acc[7].x = fmaf(r47.w, wv.x, acc[7].x); acc[7].y = fmaf(r47.w, wv.y, acc[7].y);
  }

  float bj0 = (j < V_) ? ob[j] : 0.0f;
  float bj1 = (j + 1 < V_) ? ob[j + 1] : 0.0f;
  const bool tile_full = (n0 + 128 <= V_);   // only blockIdx.x==63 is partial
#pragma unroll
  for (int r = 0; r < 8; ++r) {
    const int b = m0 + w8 + r;
    float v0 = acc[r].x + bj0;
    float v1 = acc[r].y + bj1;
    float* orow = out + ((size_t)b * T_ + t) * V_ + j;
    if (tile_full) {
      __builtin_nontemporal_store(v0, orow);
      __builtin_nontemporal_store(v1, orow + 1);
    } else {
      if (j < V_)     orow[0] = v0;
      if (j + 1 < V_) orow[1] = v1;
    }
    float bv = -INFINITY; int bi = 0;
    if (j < V_)                 { bv = v0; bi = j; }
    if (j + 1 < V_ && v1 > bv)  { bv = v1; bi = j + 1; }
#pragma unroll
    for (int off = 1; off < 64; off <<= 1) {
      float ov = __shfl_xor(bv, off, 64);
      int   oi = __shfl_xor(bi, off, 64);
      if (ov > bv || (ov == bv && oi < bi)) { bv = ov; bi = oi; }
    }
    if (lane == 0) {
      pmax[(size_t)b * NT_ + blockIdx.x] = bv;
      pidx[(size_t)b * NT_ + blockIdx.x] = bi;
    }
  }
}

// ---------------------------------------------------------------------------
extern "C" void kernel_launch(void* const* d_in, const int* in_sizes, int n_in,
                              void* d_out, int out_size, void* d_ws, size_t ws_size,
                              hipStream_t stream) {
  const int*   inputs = (const int*)  d_in[0];
  const float* eps    = (const float*)d_in[1];
  const float* emb    = (const float*)d_in[2];
  const float* inf_k  = (const float*)d_in[3];
  const float* inf_rk = (const float*)d_in[4];
  const float* inf_b  = (const float*)d_in[5];
  const float* mu_w   = (const float*)d_in[6];
  const float* mu_b   = (const float*)d_in[7];
  const float* sig_w  = (const float*)d_in[8];
  const float* sig_b  = (const float*)d_in[9];
  const float* init_w = (const float*)d_in[10];
  const float* init_b = (const float*)d_in[11];
  const float* gen_k  = (const float*)d_in[12];
  const float* gen_rk = (const float*)d_in[13];
  const float* gen_b  = (const float*)d_in[14];
  const float* out_w  = (const float*)d_in[15];
  const float* out_b  = (const float*)d_in[16];
  float* out = (float*)d_out;

  const int B = in_sizes[0] / T_;        // 256
  const int BH = B * H_;

  float* ws = (float*)d_ws;
  size_t off = 0;
  float* EK = ws + off; off += (size_t)V_ * FH_;        // emb @ gen_k
  float* XK = ws + off; off += (size_t)T_ * B * FH_;    // gathered emb @ inf_k
  float* WP = ws + off; off += (size_t)H_ * VP_;        // padded out_w
  float* hbase = ws + off; off += (size_t)4 * BH;       // hd0 cd0 hd1 cd1
  float* hd[2] = {hbase + 0 * BH, hbase + 2 * BH};
  float* cd[2] = {hbase + 1 * BH, hbase + 3 * BH};
  float* pmax = ws + off; off += (size_t)B * NT_;
  int*   pidx = (int*)(ws + off); off += (size_t)B * NT_;

  // one-time precomputes (pad + both input-projection GEMMs in one launch)
  pad_w_kernel<<<(H_ * VP_ + 255) / 256, 256, 0, stream>>>(out_w, WP);
  const int yEK = (V_ + 31) / 32;          // 256
  const int yXK = (T_ * B + 31) / 32;      // 200
  gemm_ew<<<dim3(3, yEK + yXK), 256, 0, stream>>>(emb, gen_k, EK, V_,
                                                  inf_k, XK, T_ * B,
                                                  inputs, B, yEK);

  // whole encoder + latent + decoder-init: ONE kernel (batch-parallel rows)
  encoder_all<<<B / 2, 192, 0, stream>>>(XK, inf_rk, inf_b, eps,
                                         mu_w, mu_b, sig_w, sig_b,
                                         init_w, init_b, hd[0], cd[0], B);

  // autoregressive decoder
  for (int t = 0; t < T_; ++t) {
    lstm_step<<<dim3(24, B / 16), 256, 0, stream>>>(
        EK, gen_rk, gen_b,
        hd[t & 1], cd[t & 1], hd[(t + 1) & 1], cd[(t + 1) & 1],
        pmax, pidx, (t == 0) ? 1 : 0);
    logits_argmax<<<dim3(NT_, B / 32), 256, 0, stream>>>(
        hd[(t + 1) & 1], WP, out_b, out, t, pmax, pidx);
  }
}